// Round 11
// baseline (2125.277 us; speedup 1.0000x reference)
//
#include <hip/hip_runtime.h>
#include <hip/hip_bf16.h>

#define D_DIM 1024
#define U_DIM 1024
#define B_SZ  32
#define T_SZ  2048

typedef __bf16 bf16x8 __attribute__((ext_vector_type(8)));
typedef float f32x4 __attribute__((ext_vector_type(4)));
typedef unsigned short ushort8 __attribute__((ext_vector_type(8)));
typedef unsigned short ushort4_t __attribute__((ext_vector_type(4)));

#define AS1 __attribute__((address_space(1)))
#define AS3 __attribute__((address_space(3)))

__device__ __forceinline__ unsigned short f2bf(float f) {
    union { float f; unsigned u; } v;
    v.f = f;
    unsigned r = v.u + 0x7fffu + ((v.u >> 16) & 1u);  // RNE
    return (unsigned short)(r >> 16);
}
__device__ __forceinline__ float bf2f(unsigned short h) {
    union { unsigned u; float f; } v;
    v.u = (unsigned)h << 16;
    return v.f;
}

// ---------------- K0: values fp32 -> bf16, 64B/lane ----------------
__global__ __launch_bounds__(256) void vconv2(const float* __restrict__ v,
                                              unsigned short* __restrict__ o) {
    size_t i = ((size_t)blockIdx.x * 256 + threadIdx.x) * 16;
    f32x4 a0 = *reinterpret_cast<const f32x4*>(v + i);
    f32x4 a1 = *reinterpret_cast<const f32x4*>(v + i + 4);
    f32x4 a2 = *reinterpret_cast<const f32x4*>(v + i + 8);
    f32x4 a3 = *reinterpret_cast<const f32x4*>(v + i + 12);
    ushort8 h0, h1;
    h0[0] = f2bf(a0.x); h0[1] = f2bf(a0.y); h0[2] = f2bf(a0.z); h0[3] = f2bf(a0.w);
    h0[4] = f2bf(a1.x); h0[5] = f2bf(a1.y); h0[6] = f2bf(a1.z); h0[7] = f2bf(a1.w);
    h1[0] = f2bf(a2.x); h1[1] = f2bf(a2.y); h1[2] = f2bf(a2.z); h1[3] = f2bf(a2.w);
    h1[4] = f2bf(a3.x); h1[5] = f2bf(a3.y); h1[6] = f2bf(a3.z); h1[7] = f2bf(a3.w);
    *reinterpret_cast<ushort8*>(o + i) = h0;
    *reinterpret_cast<ushort8*>(o + i + 8) = h1;
}

// ---------------- K1: W2 [D,U] fp32 -> W2t [U,D] bf16 ----------------
__global__ __launch_bounds__(256) void w2_transpose(const float* __restrict__ W2,
                                                    unsigned short* __restrict__ W2t) {
    __shared__ float tile[32][33];
    int d0 = blockIdx.x * 32, u0 = blockIdx.y * 32;
    int tx = threadIdx.x, ty = threadIdx.y;  // 32 x 8
#pragma unroll
    for (int i = 0; i < 4; i++)
        tile[ty + 8 * i][tx] = W2[(size_t)(d0 + ty + 8 * i) * U_DIM + u0 + tx];
    __syncthreads();
#pragma unroll
    for (int i = 0; i < 4; i++)
        W2t[(size_t)(u0 + ty + 8 * i) * D_DIM + d0 + tx] = f2bf(tile[tx][ty + 8 * i]);
}

// ---------------- K2: qpb[b,u] = query@W1 + b1 + b2 (fp32), K split 4-way ----------------
__global__ __launch_bounds__(256) void qproj2(const float* __restrict__ query,
                                              const float* __restrict__ W1,
                                              const float* __restrict__ b1,
                                              const float* __restrict__ b2,
                                              float* __restrict__ qpb) {
    __shared__ float red[4][64];
    const int b = blockIdx.x;
    const int u0 = blockIdx.y * 64;
    const int tid = threadIdx.x;
    const int ul = tid & 63, kq = tid >> 6;
    const int u = u0 + ul;
    float acc = 0.f;
    const float* q = query + (size_t)b * D_DIM;
#pragma unroll 4
    for (int k = kq * 256; k < kq * 256 + 256; k++)
        acc += q[k] * W1[(size_t)k * U_DIM + u];
    red[kq][ul] = acc;
    __syncthreads();
    if (tid < 64) {
        float s = red[0][tid] + red[1][tid] + red[2][tid] + red[3][tid];
        qpb[(size_t)b * U_DIM + u0 + tid] = s + b1[u0 + tid] + b2[u0 + tid];
    }
}

// ---------------- K3: fused score GEMM — A via LDS, B direct-from-L2 ----------------
// Geometry as R10: 256 rows; 4 u-passes BN=256; BK=64; 64 K-tiles; 8 waves (wm2 x wn4);
// wave 128x64; acc[8][4] (128 AGPR). LDS: A-only 2 slots x 32KB + qW/wV/red = 76 KB.
// B (W2t, 2 MB, L2-resident on every XCD) is read DIRECTLY into bq fragments via
// global_load_dwordx4 (lane lr -> row wn*64+NH*32+ni*16+lr, 16B contig in k) — the
// MFMA B-layout exists in global memory, no LDS round-trip. Removes 64KB LDS reads +
// 32KB LDS writes per tile and both asm vmcnt gates:
//   A-stage ledger (implicit): SA2(t+2,h0)@P2(t), SA2(t+2,h1)@P4(t). bq0(t+1) loads
//   issue at P1(t+1) AFTER them; the compiler's counted-vmcnt wait on bq0 before
//   P1-MFMA retires all older VMEM -> A(t+2) landed by P1(t+1), 3-phase cover; af(t)
//   reads at P1(t) see data retired one tile earlier. Phase barriers (1/phase, raw)
//   protect the rolling same-slot A overwrite exactly as R10.
__global__ __launch_bounds__(512, 2) void score_gemm13(const unsigned short* __restrict__ vbf,
                                                       const unsigned short* __restrict__ W2t,
                                                       const float* __restrict__ qpb,
                                                       const float* __restrict__ Wv,
                                                       float* __restrict__ scores) {
    __shared__ char smem[77824];
    float* qWl = (float*)(smem + 65536);   // 1024 f32
    float* wVl = (float*)(smem + 69632);   // 1024 f32
    float* redl = (float*)(smem + 73728);  // [4][256]

    const int tid = threadIdx.x, wave = tid >> 6, lane = tid & 63;
    const int lr = lane & 15, lk = lane >> 4;
    const int wm = wave >> 2, wn = wave & 3;
    const int row0 = blockIdx.x * 256;
    const int b = row0 >> 11;

    // qpb/Wv -> LDS
    qWl[tid]       = qpb[(size_t)b * U_DIM + tid];
    qWl[tid + 512] = qpb[(size_t)b * U_DIM + tid + 512];
    wVl[tid]       = Wv[tid];
    wVl[tid + 512] = Wv[tid + 512];

    // A ds_read swizzled bases (per R10)
    int pa[2];
#pragma unroll
    for (int kk = 0; kk < 2; kk++)
        pa[kk] = (wm * 128 + lr) * 128 + (((kk * 4 + lk) ^ (lr & 7)) << 4);

    // A stage addressing: LDS dest linear, global source pre-swizzled (involution)
    const int ecol = ((lane & 7) ^ (lane >> 3)) * 8;
    int aoff[2], dstA[2];
#pragma unroll
    for (int j = 0; j < 2; j++) {
        const int rowA = j * 128 + wave * 8 + (lane >> 3);
        aoff[j] = (row0 + rowA) * 1024 + ecol;
        dstA[j] = j * 16384 + wave * 1024 + lane * 16;
    }

    // B direct-load per-lane base: row wn*64 + lr, k-elems lk*8
    const unsigned short* bbase = W2t + (size_t)((wn * 64 + lr) * 1024 + lk * 8);

    auto SA2 = [&](int w, int h) {  // stage A-half h of tile w into slot w&1
#pragma unroll
        for (int j = 0; j < 2; j++)
            __builtin_amdgcn_global_load_lds(
                (const AS1 void*)(vbf + (size_t)(aoff[j] + h * 65536 + ((w & 15) << 6))),
                (AS3 void*)(smem + (w & 1) * 32768 + dstA[j] + h * 8192), 16, 0, 0);
    };

    f32x4 acc[8][4] = {};
    float s_acc[8][4] = {};
    bf16x8 bq0[2][2], bq1[2][2];

#define SBAR0 __builtin_amdgcn_sched_barrier(0);

#define RD_AF(CB, MH)                                                                 \
    _Pragma("unroll") for (int mi = 0; mi < 4; mi++)                                  \
        _Pragma("unroll") for (int kk = 0; kk < 2; kk++)                              \
            af[mi][kk] = *(const bf16x8*)(smem + (CB) + (MH) * 8192 + mi * 2048 + pa[kk]);
// B fragment direct global read: frag (NH,ni,kk) at bbase + koff + rows/k deltas
#define RD_BQG(BQ, NH, KOFF)                                                          \
    _Pragma("unroll") for (int ni = 0; ni < 2; ni++)                                  \
        _Pragma("unroll") for (int kk = 0; kk < 2; kk++)                              \
            BQ[ni][kk] = *(const bf16x8*)(bbase + (KOFF) + ((NH) * 32 + ni * 16) * 1024 + kk * 32);

#define Q16(BQ, MB, NB2)                                                              \
    __builtin_amdgcn_s_setprio(1);                                                    \
    _Pragma("unroll") for (int kk = 0; kk < 2; kk++)                                  \
        _Pragma("unroll") for (int ni = 0; ni < 2; ni++)                              \
            _Pragma("unroll") for (int mi = 0; mi < 4; mi++)                          \
                acc[(MB) + mi][(NB2) + ni] = __builtin_amdgcn_mfma_f32_16x16x32_bf16( \
                    af[mi][kk], BQ[ni][kk], acc[(MB) + mi][(NB2) + ni], 0, 0, 0);     \
    __builtin_amdgcn_s_setprio(0);

#define TILE(TT, CB, S2ON, KOFF)                                                      \
    {                                                                                 \
        bf16x8 af[4][2];                                                              \
        /* P1: (0,0) */                                                               \
        RD_AF(CB, 0)                                                                  \
        RD_BQG(bq0, 0, KOFF)                                                          \
        SBAR0 Q16(bq0, 0, 0)                                                          \
        __builtin_amdgcn_s_barrier();                                                 \
        /* P2: (0,1) */                                                               \
        RD_BQG(bq1, 1, KOFF)                                                          \
        if (S2ON) SA2((TT) + 2, 0);                                                   \
        SBAR0 Q16(bq1, 0, 2)                                                          \
        __builtin_amdgcn_s_barrier();                                                 \
        /* P3: (1,0) */                                                               \
        RD_AF(CB, 1)                                                                  \
        SBAR0 Q16(bq0, 4, 0)                                                          \
        __builtin_amdgcn_s_barrier();                                                 \
        /* P4: (1,1) */                                                               \
        if (S2ON) SA2((TT) + 2, 1);                                                   \
        SBAR0 Q16(bq1, 4, 2)                                                          \
        __builtin_amdgcn_s_barrier();                                                 \
    }

#define EPI(PS)                                                                     \
    {                                                                               \
        const int psv = (PS);                                                       \
        _Pragma("unroll") for (int n = 0; n < 4; n++) {                             \
            const int u = psv * 256 + wn * 64 + (n >> 1) * 32 + (n & 1) * 16 + lr;  \
            const float qv = qWl[u];                                                \
            const float wv = wVl[u];                                                \
            _Pragma("unroll") for (int m = 0; m < 8; m++)                           \
                _Pragma("unroll") for (int r = 0; r < 4; r++) {                     \
                    float x = acc[m][n][r] + qv;                                    \
                    float e = __expf(2.0f * x);                                     \
                    s_acc[m][r] += (1.0f - 2.0f / (e + 1.0f)) * wv;                 \
                    acc[m][n][r] = 0.f;                                             \
                }                                                                   \
        }                                                                           \
    }

    // prologue: drain qW/wV traffic; stage A tiles 0,1; wait tile 0 (keep tile 1 in flight)
    asm volatile("s_waitcnt vmcnt(0) lgkmcnt(0)" ::: "memory");
    SA2(0, 0); SA2(0, 1); SA2(1, 0); SA2(1, 1);
    asm volatile("s_waitcnt vmcnt(4)" ::: "memory");
    __builtin_amdgcn_sched_barrier(0);
    __builtin_amdgcn_s_barrier();

#pragma unroll 1
    for (int t = 0; t < 64; ++t) {
        const int cb = (t & 1) * 32768;
        const int koff = ((t >> 4) << 18) + ((t & 15) << 6);  // psn*262144 + tkn*64
        const bool st = t < 62;
        if (st) {
            TILE(t, cb, 1, koff)
        } else {
            TILE(t, cb, 0, koff)
        }
        if ((t & 15) == 15) EPI(t >> 4)
    }

#undef TILE
#undef Q16
#undef RD_AF
#undef RD_BQG
#undef SBAR0
#undef EPI

    // reduce over the 16 lr-lanes
#pragma unroll
    for (int off = 1; off < 16; off <<= 1)
#pragma unroll
        for (int m = 0; m < 8; m++)
#pragma unroll
            for (int r = 0; r < 4; r++) s_acc[m][r] += __shfl_xor(s_acc[m][r], off);

    // cross-wave (4 wn) reduce via LDS, then direct store
    __syncthreads();
    if (lr == 0) {
#pragma unroll
        for (int m = 0; m < 8; m++)
#pragma unroll
            for (int r = 0; r < 4; r++)
                redl[wn * 256 + wm * 128 + (m >> 2) * 64 + (m & 3) * 16 + lk * 4 + r] = s_acc[m][r];
    }
    __syncthreads();
    if (tid < 256) {
        float s = redl[tid] + redl[256 + tid] + redl[512 + tid] + redl[768 + tid];
        scores[row0 + tid] = s;
    }
}

// ---------------- K4: softmax over T per batch (+ zero context output) ----------------
__global__ __launch_bounds__(256) void softmax_z(const float* __restrict__ scores,
                                                 float* __restrict__ wout,
                                                 float* __restrict__ out) {
    int b = blockIdx.x, tid = threadIdx.x;
    int lane = tid & 63, wave = tid >> 6;
    __shared__ float redm[4], reds[4];
    *reinterpret_cast<f32x4*>(out + (size_t)b * D_DIM + tid * 4) = (f32x4){0.f, 0.f, 0.f, 0.f};
    float v[8];
    float mx = -3.4e38f;
#pragma unroll
    for (int i = 0; i < 8; i++) {
        v[i] = scores[(size_t)b * T_SZ + tid + i * 256];
        mx = fmaxf(mx, v[i]);
    }
#pragma unroll
    for (int off = 1; off < 64; off <<= 1) mx = fmaxf(mx, __shfl_xor(mx, off));
    if (lane == 0) redm[wave] = mx;
    __syncthreads();
    mx = fmaxf(fmaxf(redm[0], redm[1]), fmaxf(redm[2], redm[3]));
    float sum = 0.f;
#pragma unroll
    for (int i = 0; i < 8; i++) {
        v[i] = __expf(v[i] - mx);
        sum += v[i];
    }
#pragma unroll
    for (int off = 1; off < 64; off <<= 1) sum += __shfl_xor(sum, off);
    if (lane == 0) reds[wave] = sum;
    __syncthreads();
    sum = reds[0] + reds[1] + reds[2] + reds[3];
    float inv = 1.0f / sum;
#pragma unroll
    for (int i = 0; i < 8; i++) wout[(size_t)b * T_SZ + tid + i * 256] = v[i] * inv;
}

// ---------------- K5: context[b,d] = sum_t w[b,t] * values_bf16[b,t,d] ----------------
__global__ __launch_bounds__(256) void context_k(const unsigned short* __restrict__ vbf,
                                                 const float* __restrict__ w,
                                                 float* __restrict__ out) {
    int b = blockIdx.x, tc = blockIdx.y;
    int d4 = threadIdx.x;
    f32x4 acc = {0.f, 0.f, 0.f, 0.f};
    const unsigned short* vb = vbf + (size_t)b * T_SZ * D_DIM;
    int t0 = tc * 64;
#pragma unroll 2
    for (int t = t0; t < t0 + 64; ++t) {
        float wt = w[(size_t)b * T_SZ + t];
        ushort4_t hv = *reinterpret_cast<const ushort4_t*>(vb + (size_t)t * D_DIM + d4 * 4);
        acc.x += wt * bf2f(hv.x);
        acc.y += wt * bf2f(hv.y);
        acc.z += wt * bf2f(hv.z);
        acc.w += wt * bf2f(hv.w);
    }
    float* o = out + (size_t)b * D_DIM + d4 * 4;
    atomicAdd(o + 0, acc.x);
    atomicAdd(o + 1, acc.y);
    atomicAdd(o + 2, acc.z);
    atomicAdd(o + 3, acc.w);
}

extern "C" void kernel_launch(void* const* d_in, const int* in_sizes, int n_in,
                              void* d_out, int out_size, void* d_ws, size_t ws_size,
                              hipStream_t stream) {
    (void)in_sizes; (void)n_in; (void)out_size; (void)ws_size;
    const float* query  = (const float*)d_in[0];
    const float* values = (const float*)d_in[1];
    const float* W1     = (const float*)d_in[2];
    const float* b1     = (const float*)d_in[3];
    const float* W2     = (const float*)d_in[4];
    const float* b2     = (const float*)d_in[5];
    const float* Wv     = (const float*)d_in[6];
    // d_in[7] = bv: softmax is shift-invariant; scores aren't an output -> unused.

    float* out  = (float*)d_out;             // [B,D] context
    float* wout = out + B_SZ * D_DIM;        // [B,T] attention weights

    const size_t VN = (size_t)B_SZ * T_SZ * D_DIM;  // 64M elems
    char* ws = (char*)d_ws;
    unsigned short* vbf = (unsigned short*)ws;                     // 128 MB
    float* scores = (float*)(ws + VN * 2);                         // 256 KB
    float* qpb = scores + 65536;                                   // 128 KB
    unsigned short* W2t = (unsigned short*)(qpb + 32768);          // 2 MB

    vconv2<<<16384, 256, 0, stream>>>(values, vbf);
    w2_transpose<<<dim3(32, 32), dim3(32, 8), 0, stream>>>(W2, W2t);
    qproj2<<<dim3(32, 16), 256, 0, stream>>>(query, W1, b1, b2, qpb);
    score_gemm13<<<256, 512, 0, stream>>>(vbf, W2t, qpb, Wv, scores);
    softmax_z<<<B_SZ, 256, 0, stream>>>(scores, wout, out);
    context_k<<<dim3(B_SZ, 32), 256, 0, stream>>>(vbf, wout, out);
}

// Round 12
// 290.259 us; speedup vs baseline: 7.3220x; 7.3220x over previous
//
#include <hip/hip_runtime.h>
#include <hip/hip_bf16.h>

#define D_DIM 1024
#define U_DIM 1024
#define B_SZ  32
#define T_SZ  2048

typedef __bf16 bf16x8 __attribute__((ext_vector_type(8)));
typedef float f32x4 __attribute__((ext_vector_type(4)));
typedef unsigned short ushort8 __attribute__((ext_vector_type(8)));
typedef unsigned short ushort4_t __attribute__((ext_vector_type(4)));

#define AS1 __attribute__((address_space(1)))
#define AS3 __attribute__((address_space(3)))

__device__ __forceinline__ unsigned short f2bf(float f) {
    union { float f; unsigned u; } v;
    v.f = f;
    unsigned r = v.u + 0x7fffu + ((v.u >> 16) & 1u);  // RNE
    return (unsigned short)(r >> 16);
}
__device__ __forceinline__ float bf2f(unsigned short h) {
    union { unsigned u; float f; } v;
    v.u = (unsigned)h << 16;
    return v.f;
}

// ---------------- K0: values fp32 -> bf16, 64B/lane ----------------
__global__ __launch_bounds__(256) void vconv2(const float* __restrict__ v,
                                              unsigned short* __restrict__ o) {
    size_t i = ((size_t)blockIdx.x * 256 + threadIdx.x) * 16;
    f32x4 a0 = *reinterpret_cast<const f32x4*>(v + i);
    f32x4 a1 = *reinterpret_cast<const f32x4*>(v + i + 4);
    f32x4 a2 = *reinterpret_cast<const f32x4*>(v + i + 8);
    f32x4 a3 = *reinterpret_cast<const f32x4*>(v + i + 12);
    ushort8 h0, h1;
    h0[0] = f2bf(a0.x); h0[1] = f2bf(a0.y); h0[2] = f2bf(a0.z); h0[3] = f2bf(a0.w);
    h0[4] = f2bf(a1.x); h0[5] = f2bf(a1.y); h0[6] = f2bf(a1.z); h0[7] = f2bf(a1.w);
    h1[0] = f2bf(a2.x); h1[1] = f2bf(a2.y); h1[2] = f2bf(a2.z); h1[3] = f2bf(a2.w);
    h1[4] = f2bf(a3.x); h1[5] = f2bf(a3.y); h1[6] = f2bf(a3.z); h1[7] = f2bf(a3.w);
    *reinterpret_cast<ushort8*>(o + i) = h0;
    *reinterpret_cast<ushort8*>(o + i + 8) = h1;
}

// ---------------- K1: W2 [D,U] fp32 -> W2t [U,D] bf16 ----------------
__global__ __launch_bounds__(256) void w2_transpose(const float* __restrict__ W2,
                                                    unsigned short* __restrict__ W2t) {
    __shared__ float tile[32][33];
    int d0 = blockIdx.x * 32, u0 = blockIdx.y * 32;
    int tx = threadIdx.x, ty = threadIdx.y;  // 32 x 8
#pragma unroll
    for (int i = 0; i < 4; i++)
        tile[ty + 8 * i][tx] = W2[(size_t)(d0 + ty + 8 * i) * U_DIM + u0 + tx];
    __syncthreads();
#pragma unroll
    for (int i = 0; i < 4; i++)
        W2t[(size_t)(u0 + ty + 8 * i) * D_DIM + d0 + tx] = f2bf(tile[tx][ty + 8 * i]);
}

// ---------------- K2: qpb[b,u] = query@W1 + b1 + b2 (fp32), K split 4-way ----------------
__global__ __launch_bounds__(256) void qproj2(const float* __restrict__ query,
                                              const float* __restrict__ W1,
                                              const float* __restrict__ b1,
                                              const float* __restrict__ b2,
                                              float* __restrict__ qpb) {
    __shared__ float red[4][64];
    const int b = blockIdx.x;
    const int u0 = blockIdx.y * 64;
    const int tid = threadIdx.x;
    const int ul = tid & 63, kq = tid >> 6;
    const int u = u0 + ul;
    float acc = 0.f;
    const float* q = query + (size_t)b * D_DIM;
#pragma unroll 4
    for (int k = kq * 256; k < kq * 256 + 256; k++)
        acc += q[k] * W1[(size_t)k * U_DIM + u];
    red[kq][ul] = acc;
    __syncthreads();
    if (tid < 64) {
        float s = red[0][tid] + red[1][tid] + red[2][tid] + red[3][tid];
        qpb[(size_t)b * U_DIM + u0 + tid] = s + b1[u0 + tid] + b2[u0 + tid];
    }
}

// ---------------- K3: fused score GEMM — R10 structure, single vmcnt gate/tile ----------------
// Geometry as R10 (proven): 256 rows; 4 u-passes BN=256; BK=64; 64 K-tiles; 8 waves
// (wm2 x wn4); wave 128x64; acc[8][4] AGPR. LDS 2x64KB slots + qW/wV/red = 140 KB.
// Phase = { frag ds_reads (plain deref -> compiler-counted lgkm); stage; sched0;
//           setprio1; 16 MFMA; setprio0; [gate @P4 only]; s_barrier }.
// Stages: P1: Bh1(t+1); P2: Ah0(t+2); P4: Bh0(t+2), Ah1(t+2).
// Single-gate ledger: prologue issues 14 loads [tile0 x4, Ah0/Bh0/Ah1(1)], VMW(6)
// retires tile 0. Steady: at P4(t)-end in-flight = 14; vmcnt(6) retires the 8 oldest
// = ALL FOUR halves of tile t+1 (cover >= 3 phases each); leaves tile t+2's 6.
// Tail: t=62 stages only Bh1(63), gate VMW(0) drains; t=63 gate-free.
// Hoisting safety: the gate's "memory" clobber pins all later ds_reads below it;
// everything below the gate reads retired DMA data. Slot WAR: P1 reads are lgkm-
// drained before P1's closing barrier; overwriting stage issues after it (as R10).
__global__ __launch_bounds__(512, 2) void score_gemm14(const unsigned short* __restrict__ vbf,
                                                       const unsigned short* __restrict__ W2t,
                                                       const float* __restrict__ qpb,
                                                       const float* __restrict__ Wv,
                                                       float* __restrict__ scores) {
    __shared__ char smem[143360];
    float* qWl = (float*)(smem + 131072);   // 1024 f32
    float* wVl = (float*)(smem + 135168);   // 1024 f32
    float* redl = (float*)(smem + 139264);  // [4][256]

    const int tid = threadIdx.x, wave = tid >> 6, lane = tid & 63;
    const int lr = lane & 15, lk = lane >> 4;
    const int wm = wave >> 2, wn = wave & 3;
    const int row0 = blockIdx.x * 256;
    const int b = row0 >> 11;

    // qpb/Wv -> LDS (epilogues issue no vmem; vmcnt ledger stays exact)
    qWl[tid]       = qpb[(size_t)b * U_DIM + tid];
    qWl[tid + 512] = qpb[(size_t)b * U_DIM + tid + 512];
    wVl[tid]       = Wv[tid];
    wVl[tid + 512] = Wv[tid + 512];

    // ds_read swizzled bases
    int pa[2], pb[2];
#pragma unroll
    for (int kk = 0; kk < 2; kk++) {
        pa[kk] = (wm * 128 + lr) * 128 + (((kk * 4 + lk) ^ (lr & 7)) << 4);
        pb[kk] = (wn * 64 + lr) * 128 + (((kk * 4 + lk) ^ (lr & 7)) << 4);
    }

    // stage addressing: LDS dest linear, global source pre-swizzled (involution)
    const int ecol = ((lane & 7) ^ (lane >> 3)) * 8;
    int aoff[2], dstA[2], boff[2], dstB[2];
#pragma unroll
    for (int j = 0; j < 2; j++) {
        const int rowA = j * 128 + wave * 8 + (lane >> 3);
        aoff[j] = (row0 + rowA) * 1024 + ecol;
        dstA[j] = j * 16384 + wave * 1024 + lane * 16;
        const int idx = wave * 2 + j, s = idx >> 2, l = idx & 3;
        const int rowB = s * 64 + l * 8 + (lane >> 3);
        boff[j] = rowB * 1024 + ecol;
        dstB[j] = 32768 + s * 8192 + l * 1024 + lane * 16;
    }

    auto SA2 = [&](int w, int h) {  // stage A-half h of tile w into slot w&1
#pragma unroll
        for (int j = 0; j < 2; j++)
            __builtin_amdgcn_global_load_lds(
                (const AS1 void*)(vbf + (size_t)(aoff[j] + h * 65536 + ((w & 15) << 6))),
                (AS3 void*)(smem + (w & 1) * 65536 + dstA[j] + h * 8192), 16, 0, 0);
    };
    auto SB2 = [&](int w, int h) {  // stage B-half h of tile w into slot w&1
#pragma unroll
        for (int j = 0; j < 2; j++)
            __builtin_amdgcn_global_load_lds(
                (const AS1 void*)(W2t + (size_t)(boff[j] + ((w >> 4) << 18) + h * 32768 +
                                                 ((w & 15) << 6))),
                (AS3 void*)(smem + (w & 1) * 65536 + dstB[j] + h * 4096), 16, 0, 0);
    };

    f32x4 acc[8][4] = {};
    float s_acc[8][4] = {};
    bf16x8 bq0[2][2], bq1[2][2];

#define VMW(N) asm volatile("s_waitcnt vmcnt(" #N ")" ::: "memory")
#define NOGATE (void)0
#define SBAR0 __builtin_amdgcn_sched_barrier(0);

#define RD_AF(CB, MH)                                                                 \
    _Pragma("unroll") for (int mi = 0; mi < 4; mi++)                                  \
        _Pragma("unroll") for (int kk = 0; kk < 2; kk++)                              \
            af[mi][kk] = *(const bf16x8*)(smem + (CB) + (MH) * 8192 + mi * 2048 + pa[kk]);
#define RD_BQ(BQ, CB, NH)                                                             \
    _Pragma("unroll") for (int ni = 0; ni < 2; ni++)                                  \
        _Pragma("unroll") for (int kk = 0; kk < 2; kk++)                              \
            BQ[ni][kk] = *(const bf16x8*)(smem + (CB) + 32768 + (NH) * 4096 + ni * 2048 + pb[kk]);

#define Q16(BQ, MB, NB2)                                                              \
    __builtin_amdgcn_s_setprio(1);                                                    \
    _Pragma("unroll") for (int kk = 0; kk < 2; kk++)                                  \
        _Pragma("unroll") for (int ni = 0; ni < 2; ni++)                              \
            _Pragma("unroll") for (int mi = 0; mi < 4; mi++)                          \
                acc[(MB) + mi][(NB2) + ni] = __builtin_amdgcn_mfma_f32_16x16x32_bf16( \
                    af[mi][kk], BQ[ni][kk], acc[(MB) + mi][(NB2) + ni], 0, 0, 0);     \
    __builtin_amdgcn_s_setprio(0);

#define TILE(TT, CB, S1ON, S2ON, G4)                                                  \
    {                                                                                 \
        bf16x8 af[4][2];                                                              \
        /* P1: (0,0) */                                                               \
        RD_AF(CB, 0)                                                                  \
        RD_BQ(bq0, CB, 0)                                                             \
        if (S1ON) SB2((TT) + 1, 1);                                                   \
        SBAR0 Q16(bq0, 0, 0)                                                          \
        __builtin_amdgcn_s_barrier();                                                 \
        /* P2: (0,1) */                                                               \
        RD_BQ(bq1, CB, 1)                                                             \
        if (S2ON) SA2((TT) + 2, 0);                                                   \
        SBAR0 Q16(bq1, 0, 2)                                                          \
        __builtin_amdgcn_s_barrier();                                                 \
        /* P3: (1,0) */                                                               \
        RD_AF(CB, 1)                                                                  \
        SBAR0 Q16(bq0, 4, 0)                                                          \
        __builtin_amdgcn_s_barrier();                                                 \
        /* P4: (1,1) */                                                               \
        if (S2ON) { SB2((TT) + 2, 0); SA2((TT) + 2, 1); }                             \
        SBAR0 Q16(bq1, 4, 2) G4;                                                      \
        __builtin_amdgcn_s_barrier();                                                 \
    }

#define EPI(PS)                                                                     \
    {                                                                               \
        const int psv = (PS);                                                       \
        _Pragma("unroll") for (int n = 0; n < 4; n++) {                             \
            const int u = psv * 256 + wn * 64 + (n >> 1) * 32 + (n & 1) * 16 + lr;  \
            const float qv = qWl[u];                                                \
            const float wv = wVl[u];                                                \
            _Pragma("unroll") for (int m = 0; m < 8; m++)                           \
                _Pragma("unroll") for (int r = 0; r < 4; r++) {                     \
                    float x = acc[m][n][r] + qv;                                    \
                    float e = __expf(2.0f * x);                                     \
                    s_acc[m][r] += (1.0f - 2.0f / (e + 1.0f)) * wv;                 \
                    acc[m][n][r] = 0.f;                                             \
                }                                                                   \
        }                                                                           \
    }

    // prologue: drain qW/wV; stage tile0 (first 8 loads) + tile1 {Ah0,Bh0,Ah1};
    // VMW(6) retires exactly tile 0's four halves.
    asm volatile("s_waitcnt vmcnt(0) lgkmcnt(0)" ::: "memory");
    SA2(0, 0); SB2(0, 0); SA2(0, 1); SB2(0, 1);
    SA2(1, 0); SB2(1, 0); SA2(1, 1);
    VMW(6);
    __builtin_amdgcn_sched_barrier(0);
    __builtin_amdgcn_s_barrier();

#pragma unroll 1
    for (int s2 = 0; s2 < 31; ++s2) {
        const int te = 2 * s2;
        TILE(te, 0, 1, 1, VMW(6))
        TILE(te + 1, 65536, 1, 1, VMW(6))
        if ((s2 & 7) == 7) EPI(s2 >> 3)
    }
    TILE(62, 0, 1, 0, VMW(0))
    TILE(63, 65536, 0, 0, NOGATE)
    EPI(3)

#undef TILE
#undef Q16
#undef RD_AF
#undef RD_BQ
#undef SBAR0
#undef VMW
#undef NOGATE
#undef EPI

    // reduce over the 16 lr-lanes
#pragma unroll
    for (int off = 1; off < 16; off <<= 1)
#pragma unroll
        for (int m = 0; m < 8; m++)
#pragma unroll
            for (int r = 0; r < 4; r++) s_acc[m][r] += __shfl_xor(s_acc[m][r], off);

    // cross-wave (4 wn) reduce via LDS, then direct store
    __syncthreads();
    if (lr == 0) {
#pragma unroll
        for (int m = 0; m < 8; m++)
#pragma unroll
            for (int r = 0; r < 4; r++)
                redl[wn * 256 + wm * 128 + (m >> 2) * 64 + (m & 3) * 16 + lk * 4 + r] = s_acc[m][r];
    }
    __syncthreads();
    if (tid < 256) {
        float s = redl[tid] + redl[256 + tid] + redl[512 + tid] + redl[768 + tid];
        scores[row0 + tid] = s;
    }
}

// ---------------- K4: softmax over T per batch ----------------
__global__ __launch_bounds__(256) void softmax_k(const float* __restrict__ scores,
                                                 float* __restrict__ wout) {
    int b = blockIdx.x, tid = threadIdx.x;
    int lane = tid & 63, wave = tid >> 6;
    __shared__ float redm[4], reds[4];
    float v[8];
    float mx = -3.4e38f;
#pragma unroll
    for (int i = 0; i < 8; i++) {
        v[i] = scores[(size_t)b * T_SZ + tid + i * 256];
        mx = fmaxf(mx, v[i]);
    }
#pragma unroll
    for (int off = 1; off < 64; off <<= 1) mx = fmaxf(mx, __shfl_xor(mx, off));
    if (lane == 0) redm[wave] = mx;
    __syncthreads();
    mx = fmaxf(fmaxf(redm[0], redm[1]), fmaxf(redm[2], redm[3]));
    float sum = 0.f;
#pragma unroll
    for (int i = 0; i < 8; i++) {
        v[i] = __expf(v[i] - mx);
        sum += v[i];
    }
#pragma unroll
    for (int off = 1; off < 64; off <<= 1) sum += __shfl_xor(sum, off);
    if (lane == 0) reds[wave] = sum;
    __syncthreads();
    sum = reds[0] + reds[1] + reds[2] + reds[3];
    float inv = 1.0f / sum;
#pragma unroll
    for (int i = 0; i < 8; i++) wout[(size_t)b * T_SZ + tid + i * 256] = v[i] * inv;
}

// ---------------- K5a: context partials — part[tc][b][d] = sum_{t in tc} w*v ----------------
__global__ __launch_bounds__(256) void context_part(const unsigned short* __restrict__ vbf,
                                                    const float* __restrict__ w,
                                                    float* __restrict__ part) {
    const int b = blockIdx.x, tc = blockIdx.y;
    const int d4 = threadIdx.x;
    f32x4 acc = {0.f, 0.f, 0.f, 0.f};
    const unsigned short* vb = vbf + (size_t)b * T_SZ * D_DIM;
    const int t0 = tc * 256;
#pragma unroll 2
    for (int t = t0; t < t0 + 256; ++t) {
        float wt = w[(size_t)b * T_SZ + t];
        ushort4_t hv = *reinterpret_cast<const ushort4_t*>(vb + (size_t)t * D_DIM + d4 * 4);
        acc.x += wt * bf2f(hv.x);
        acc.y += wt * bf2f(hv.y);
        acc.z += wt * bf2f(hv.z);
        acc.w += wt * bf2f(hv.w);
    }
    *reinterpret_cast<f32x4*>(part + ((size_t)tc * B_SZ + b) * D_DIM + d4 * 4) = acc;
}

// ---------------- K5b: context reduce — out[b][d] = sum_tc part[tc][b][d] ----------------
__global__ __launch_bounds__(256) void context_red(const float* __restrict__ part,
                                                   float* __restrict__ out) {
    const int b = blockIdx.x;
    const int d4 = threadIdx.x;
    f32x4 s = {0.f, 0.f, 0.f, 0.f};
#pragma unroll
    for (int p = 0; p < 8; ++p)
        s += *reinterpret_cast<const f32x4*>(part + ((size_t)p * B_SZ + b) * D_DIM + d4 * 4);
    *reinterpret_cast<f32x4*>(out + (size_t)b * D_DIM + d4 * 4) = s;
}

extern "C" void kernel_launch(void* const* d_in, const int* in_sizes, int n_in,
                              void* d_out, int out_size, void* d_ws, size_t ws_size,
                              hipStream_t stream) {
    (void)in_sizes; (void)n_in; (void)out_size; (void)ws_size;
    const float* query  = (const float*)d_in[0];
    const float* values = (const float*)d_in[1];
    const float* W1     = (const float*)d_in[2];
    const float* b1     = (const float*)d_in[3];
    const float* W2     = (const float*)d_in[4];
    const float* b2     = (const float*)d_in[5];
    const float* Wv     = (const float*)d_in[6];
    // d_in[7] = bv: softmax is shift-invariant; scores aren't an output -> unused.

    float* out  = (float*)d_out;             // [B,D] context
    float* wout = out + B_SZ * D_DIM;        // [B,T] attention weights

    const size_t VN = (size_t)B_SZ * T_SZ * D_DIM;  // 64M elems
    char* ws = (char*)d_ws;
    unsigned short* vbf = (unsigned short*)ws;                     // 128 MB
    float* scores = (float*)(ws + VN * 2);                         // 256 KB
    float* qpb = scores + 65536;                                   // 128 KB
    unsigned short* W2t = (unsigned short*)(qpb + 32768);          // 2 MB
    float* part = (float*)W2t;  // aliases W2t (dead after gemm); 8*32*1024 f32 = 1 MB

    vconv2<<<16384, 256, 0, stream>>>(values, vbf);
    w2_transpose<<<dim3(32, 32), dim3(32, 8), 0, stream>>>(W2, W2t);
    qproj2<<<dim3(32, 16), 256, 0, stream>>>(query, W1, b1, b2, qpb);
    score_gemm14<<<256, 512, 0, stream>>>(vbf, W2t, qpb, Wv, scores);
    softmax_k<<<B_SZ, 256, 0, stream>>>(scores, wout);
    context_part<<<dim3(B_SZ, 8), 256, 0, stream>>>(vbf, wout, part);
    context_red<<<B_SZ, 256, 0, stream>>>(part, out);
}

// Round 13
// 255.932 us; speedup vs baseline: 8.3041x; 1.1341x over previous
//
#include <hip/hip_runtime.h>
#include <hip/hip_bf16.h>

#define D_DIM 1024
#define U_DIM 1024
#define B_SZ  32
#define T_SZ  2048

typedef __bf16 bf16x8 __attribute__((ext_vector_type(8)));
typedef float f32x4 __attribute__((ext_vector_type(4)));
typedef unsigned short ushort8 __attribute__((ext_vector_type(8)));
typedef unsigned short ushort4_t __attribute__((ext_vector_type(4)));

#define AS1 __attribute__((address_space(1)))
#define AS3 __attribute__((address_space(3)))

__device__ __forceinline__ unsigned short f2bf(float f) {
    union { float f; unsigned u; } v;
    v.f = f;
    unsigned r = v.u + 0x7fffu + ((v.u >> 16) & 1u);  // RNE
    return (unsigned short)(r >> 16);
}
__device__ __forceinline__ float bf2f(unsigned short h) {
    union { unsigned u; float f; } v;
    v.u = (unsigned)h << 16;
    return v.f;
}

// ---------------- K1 (merged prep): w2t + qproj first (tail overlap), then vconv bulk ----------------
// blocks [0,1024): W2 [D,U] fp32 -> W2t [U,D] bf16
// blocks [1024,1536): qpb[b,u] = query@W1 + b1 + b2 (fp32), K split 4-way
// blocks [1536,17920): values fp32 -> bf16, 64B/lane, no loop (exact R4 vconv2 form)
__global__ __launch_bounds__(256) void prep2(const float* __restrict__ v,
                                             unsigned short* __restrict__ vbf,
                                             const float* __restrict__ W2,
                                             unsigned short* __restrict__ W2t,
                                             const float* __restrict__ query,
                                             const float* __restrict__ W1,
                                             const float* __restrict__ b1,
                                             const float* __restrict__ b2,
                                             float* __restrict__ qpb) {
    __shared__ float tile[32][33];
    __shared__ float red[4][64];
    const int blk = blockIdx.x;
    const int tid = threadIdx.x;
    if (blk < 1024) {
        // W2 transpose
        const int d0 = (blk & 31) * 32, u0 = (blk >> 5) * 32;
        const int tx = tid & 31, ty = tid >> 5;  // 32 x 8
#pragma unroll
        for (int i = 0; i < 4; i++)
            tile[ty + 8 * i][tx] = W2[(size_t)(d0 + ty + 8 * i) * U_DIM + u0 + tx];
        __syncthreads();
#pragma unroll
        for (int i = 0; i < 4; i++)
            W2t[(size_t)(u0 + ty + 8 * i) * D_DIM + d0 + tx] = f2bf(tile[tx][ty + 8 * i]);
    } else if (blk < 1536) {
        // qproj
        const int q = blk - 1024;          // 0..511
        const int b = q & 31;
        const int u0 = (q >> 5) * 64;
        const int ul = tid & 63, kq = tid >> 6;
        const int u = u0 + ul;
        float acc = 0.f;
        const float* qr = query + (size_t)b * D_DIM;
#pragma unroll 4
        for (int k = kq * 256; k < kq * 256 + 256; k++)
            acc += qr[k] * W1[(size_t)k * U_DIM + u];
        red[kq][ul] = acc;
        __syncthreads();
        if (tid < 64) {
            float s = red[0][tid] + red[1][tid] + red[2][tid] + red[3][tid];
            qpb[(size_t)b * U_DIM + u0 + tid] = s + b1[u0 + tid] + b2[u0 + tid];
        }
    } else {
        // vconv: 16384 blocks, 16 floats/thread
        size_t i = ((size_t)(blk - 1536) * 256 + tid) * 16;
        f32x4 a0 = *reinterpret_cast<const f32x4*>(v + i);
        f32x4 a1 = *reinterpret_cast<const f32x4*>(v + i + 4);
        f32x4 a2 = *reinterpret_cast<const f32x4*>(v + i + 8);
        f32x4 a3 = *reinterpret_cast<const f32x4*>(v + i + 12);
        ushort8 h0, h1;
        h0[0] = f2bf(a0.x); h0[1] = f2bf(a0.y); h0[2] = f2bf(a0.z); h0[3] = f2bf(a0.w);
        h0[4] = f2bf(a1.x); h0[5] = f2bf(a1.y); h0[6] = f2bf(a1.z); h0[7] = f2bf(a1.w);
        h1[0] = f2bf(a2.x); h1[1] = f2bf(a2.y); h1[2] = f2bf(a2.z); h1[3] = f2bf(a2.w);
        h1[4] = f2bf(a3.x); h1[5] = f2bf(a3.y); h1[6] = f2bf(a3.z); h1[7] = f2bf(a3.w);
        *reinterpret_cast<ushort8*>(vbf + i) = h0;
        *reinterpret_cast<ushort8*>(vbf + i + 8) = h1;
    }
}

// ---------------- K3: fused score GEMM — R12 structure (frozen; proven 161-167 µs) ----------------
// 256 rows; 4 u-passes BN=256; BK=64; 64 K-tiles; 8 waves (wm2 x wn4); wave 128x64;
// acc[8][4] AGPR. LDS 2x64KB slots + qW/wV/red = 140 KB. Single vmcnt gate per tile.
// Stages: P1: Bh1(t+1); P2: Ah0(t+2); P4: Bh0(t+2), Ah1(t+2).
// Ledger: prologue 14 loads, VMW(6) retires tile 0. Steady: gate @P4 vmcnt(6) retires
// all four halves of tile t+1. Tail: t=62 gate VMW(0); t=63 gate-free.
__global__ __launch_bounds__(512, 2) void score_gemm14(const unsigned short* __restrict__ vbf,
                                                       const unsigned short* __restrict__ W2t,
                                                       const float* __restrict__ qpb,
                                                       const float* __restrict__ Wv,
                                                       float* __restrict__ scores) {
    __shared__ char smem[143360];
    float* qWl = (float*)(smem + 131072);   // 1024 f32
    float* wVl = (float*)(smem + 135168);   // 1024 f32
    float* redl = (float*)(smem + 139264);  // [4][256]

    const int tid = threadIdx.x, wave = tid >> 6, lane = tid & 63;
    const int lr = lane & 15, lk = lane >> 4;
    const int wm = wave >> 2, wn = wave & 3;
    const int row0 = blockIdx.x * 256;
    const int b = row0 >> 11;

    qWl[tid]       = qpb[(size_t)b * U_DIM + tid];
    qWl[tid + 512] = qpb[(size_t)b * U_DIM + tid + 512];
    wVl[tid]       = Wv[tid];
    wVl[tid + 512] = Wv[tid + 512];

    int pa[2], pb[2];
#pragma unroll
    for (int kk = 0; kk < 2; kk++) {
        pa[kk] = (wm * 128 + lr) * 128 + (((kk * 4 + lk) ^ (lr & 7)) << 4);
        pb[kk] = (wn * 64 + lr) * 128 + (((kk * 4 + lk) ^ (lr & 7)) << 4);
    }

    const int ecol = ((lane & 7) ^ (lane >> 3)) * 8;
    int aoff[2], dstA[2], boff[2], dstB[2];
#pragma unroll
    for (int j = 0; j < 2; j++) {
        const int rowA = j * 128 + wave * 8 + (lane >> 3);
        aoff[j] = (row0 + rowA) * 1024 + ecol;
        dstA[j] = j * 16384 + wave * 1024 + lane * 16;
        const int idx = wave * 2 + j, s = idx >> 2, l = idx & 3;
        const int rowB = s * 64 + l * 8 + (lane >> 3);
        boff[j] = rowB * 1024 + ecol;
        dstB[j] = 32768 + s * 8192 + l * 1024 + lane * 16;
    }

    auto SA2 = [&](int w, int h) {
#pragma unroll
        for (int j = 0; j < 2; j++)
            __builtin_amdgcn_global_load_lds(
                (const AS1 void*)(vbf + (size_t)(aoff[j] + h * 65536 + ((w & 15) << 6))),
                (AS3 void*)(smem + (w & 1) * 65536 + dstA[j] + h * 8192), 16, 0, 0);
    };
    auto SB2 = [&](int w, int h) {
#pragma unroll
        for (int j = 0; j < 2; j++)
            __builtin_amdgcn_global_load_lds(
                (const AS1 void*)(W2t + (size_t)(boff[j] + ((w >> 4) << 18) + h * 32768 +
                                                 ((w & 15) << 6))),
                (AS3 void*)(smem + (w & 1) * 65536 + dstB[j] + h * 4096), 16, 0, 0);
    };

    f32x4 acc[8][4] = {};
    float s_acc[8][4] = {};
    bf16x8 bq0[2][2], bq1[2][2];

#define VMW(N) asm volatile("s_waitcnt vmcnt(" #N ")" ::: "memory")
#define NOGATE (void)0
#define SBAR0 __builtin_amdgcn_sched_barrier(0);

#define RD_AF(CB, MH)                                                                 \
    _Pragma("unroll") for (int mi = 0; mi < 4; mi++)                                  \
        _Pragma("unroll") for (int kk = 0; kk < 2; kk++)                              \
            af[mi][kk] = *(const bf16x8*)(smem + (CB) + (MH) * 8192 + mi * 2048 + pa[kk]);
#define RD_BQ(BQ, CB, NH)                                                             \
    _Pragma("unroll") for (int ni = 0; ni < 2; ni++)                                  \
        _Pragma("unroll") for (int kk = 0; kk < 2; kk++)                              \
            BQ[ni][kk] = *(const bf16x8*)(smem + (CB) + 32768 + (NH) * 4096 + ni * 2048 + pb[kk]);

#define Q16(BQ, MB, NB2)                                                              \
    __builtin_amdgcn_s_setprio(1);                                                    \
    _Pragma("unroll") for (int kk = 0; kk < 2; kk++)                                  \
        _Pragma("unroll") for (int ni = 0; ni < 2; ni++)                              \
            _Pragma("unroll") for (int mi = 0; mi < 4; mi++)                          \
                acc[(MB) + mi][(NB2) + ni] = __builtin_amdgcn_mfma_f32_16x16x32_bf16( \
                    af[mi][kk], BQ[ni][kk], acc[(MB) + mi][(NB2) + ni], 0, 0, 0);     \
    __builtin_amdgcn_s_setprio(0);

#define TILE(TT, CB, S1ON, S2ON, G4)                                                  \
    {                                                                                 \
        bf16x8 af[4][2];                                                              \
        RD_AF(CB, 0)                                                                  \
        RD_BQ(bq0, CB, 0)                                                             \
        if (S1ON) SB2((TT) + 1, 1);                                                   \
        SBAR0 Q16(bq0, 0, 0)                                                          \
        __builtin_amdgcn_s_barrier();                                                 \
        RD_BQ(bq1, CB, 1)                                                             \
        if (S2ON) SA2((TT) + 2, 0);                                                   \
        SBAR0 Q16(bq1, 0, 2)                                                          \
        __builtin_amdgcn_s_barrier();                                                 \
        RD_AF(CB, 1)                                                                  \
        SBAR0 Q16(bq0, 4, 0)                                                          \
        __builtin_amdgcn_s_barrier();                                                 \
        if (S2ON) { SB2((TT) + 2, 0); SA2((TT) + 2, 1); }                             \
        SBAR0 Q16(bq1, 4, 2) G4;                                                      \
        __builtin_amdgcn_s_barrier();                                                 \
    }

#define EPI(PS)                                                                     \
    {                                                                               \
        const int psv = (PS);                                                       \
        _Pragma("unroll") for (int n = 0; n < 4; n++) {                             \
            const int u = psv * 256 + wn * 64 + (n >> 1) * 32 + (n & 1) * 16 + lr;  \
            const float qv = qWl[u];                                                \
            const float wv = wVl[u];                                                \
            _Pragma("unroll") for (int m = 0; m < 8; m++)                           \
                _Pragma("unroll") for (int r = 0; r < 4; r++) {                     \
                    float x = acc[m][n][r] + qv;                                    \
                    float e = __expf(2.0f * x);                                     \
                    s_acc[m][r] += (1.0f - 2.0f / (e + 1.0f)) * wv;                 \
                    acc[m][n][r] = 0.f;                                             \
                }                                                                   \
        }                                                                           \
    }

    asm volatile("s_waitcnt vmcnt(0) lgkmcnt(0)" ::: "memory");
    SA2(0, 0); SB2(0, 0); SA2(0, 1); SB2(0, 1);
    SA2(1, 0); SB2(1, 0); SA2(1, 1);
    VMW(6);
    __builtin_amdgcn_sched_barrier(0);
    __builtin_amdgcn_s_barrier();

#pragma unroll 1
    for (int s2 = 0; s2 < 31; ++s2) {
        const int te = 2 * s2;
        TILE(te, 0, 1, 1, VMW(6))
        TILE(te + 1, 65536, 1, 1, VMW(6))
        if ((s2 & 7) == 7) EPI(s2 >> 3)
    }
    TILE(62, 0, 1, 0, VMW(0))
    TILE(63, 65536, 0, 0, NOGATE)
    EPI(3)

#undef TILE
#undef Q16
#undef RD_AF
#undef RD_BQ
#undef SBAR0
#undef VMW
#undef NOGATE
#undef EPI

#pragma unroll
    for (int off = 1; off < 16; off <<= 1)
#pragma unroll
        for (int m = 0; m < 8; m++)
#pragma unroll
            for (int r = 0; r < 4; r++) s_acc[m][r] += __shfl_xor(s_acc[m][r], off);

    __syncthreads();
    if (lr == 0) {
#pragma unroll
        for (int m = 0; m < 8; m++)
#pragma unroll
            for (int r = 0; r < 4; r++)
                redl[wn * 256 + wm * 128 + (m >> 2) * 64 + (m & 3) * 16 + lk * 4 + r] = s_acc[m][r];
    }
    __syncthreads();
    if (tid < 256) {
        float s = redl[tid] + redl[256 + tid] + redl[512 + tid] + redl[768 + tid];
        scores[row0 + tid] = s;
    }
}

// ---------------- K4: softmax over T per batch ----------------
__global__ __launch_bounds__(256) void softmax_k(const float* __restrict__ scores,
                                                 float* __restrict__ wout) {
    int b = blockIdx.x, tid = threadIdx.x;
    int lane = tid & 63, wave = tid >> 6;
    __shared__ float redm[4], reds[4];
    float v[8];
    float mx = -3.4e38f;
#pragma unroll
    for (int i = 0; i < 8; i++) {
        v[i] = scores[(size_t)b * T_SZ + tid + i * 256];
        mx = fmaxf(mx, v[i]);
    }
#pragma unroll
    for (int off = 1; off < 64; off <<= 1) mx = fmaxf(mx, __shfl_xor(mx, off));
    if (lane == 0) redm[wave] = mx;
    __syncthreads();
    mx = fmaxf(fmaxf(redm[0], redm[1]), fmaxf(redm[2], redm[3]));
    float sum = 0.f;
#pragma unroll
    for (int i = 0; i < 8; i++) {
        v[i] = __expf(v[i] - mx);
        sum += v[i];
    }
#pragma unroll
    for (int off = 1; off < 64; off <<= 1) sum += __shfl_xor(sum, off);
    if (lane == 0) reds[wave] = sum;
    __syncthreads();
    sum = reds[0] + reds[1] + reds[2] + reds[3];
    float inv = 1.0f / sum;
#pragma unroll
    for (int i = 0; i < 8; i++) wout[(size_t)b * T_SZ + tid + i * 256] = v[i] * inv;
}

// ---------------- K5a: context partials — part[tc][b][d] = sum_{t in tc} w*v ----------------
__global__ __launch_bounds__(256) void context_part(const unsigned short* __restrict__ vbf,
                                                    const float* __restrict__ w,
                                                    float* __restrict__ part) {
    const int b = blockIdx.x, tc = blockIdx.y;
    const int d4 = threadIdx.x;
    f32x4 acc = {0.f, 0.f, 0.f, 0.f};
    const unsigned short* vb = vbf + (size_t)b * T_SZ * D_DIM;
    const int t0 = tc * 128;
#pragma unroll 2
    for (int t = t0; t < t0 + 128; ++t) {
        float wt = w[(size_t)b * T_SZ + t];
        ushort4_t hv = *reinterpret_cast<const ushort4_t*>(vb + (size_t)t * D_DIM + d4 * 4);
        acc.x += wt * bf2f(hv.x);
        acc.y += wt * bf2f(hv.y);
        acc.z += wt * bf2f(hv.z);
        acc.w += wt * bf2f(hv.w);
    }
    *reinterpret_cast<f32x4*>(part + ((size_t)tc * B_SZ + b) * D_DIM + d4 * 4) = acc;
}

// ---------------- K5b: context reduce — out[b][d] = sum_tc part[tc][b][d] ----------------
__global__ __launch_bounds__(256) void context_red(const float* __restrict__ part,
                                                   float* __restrict__ out) {
    const int b = blockIdx.x;
    const int d4 = threadIdx.x;
    f32x4 s = {0.f, 0.f, 0.f, 0.f};
#pragma unroll
    for (int p = 0; p < 16; ++p)
        s += *reinterpret_cast<const f32x4*>(part + ((size_t)p * B_SZ + b) * D_DIM + d4 * 4);
    *reinterpret_cast<f32x4*>(out + (size_t)b * D_DIM + d4 * 4) = s;
}

extern "C" void kernel_launch(void* const* d_in, const int* in_sizes, int n_in,
                              void* d_out, int out_size, void* d_ws, size_t ws_size,
                              hipStream_t stream) {
    (void)in_sizes; (void)n_in; (void)out_size; (void)ws_size;
    const float* query  = (const float*)d_in[0];
    const float* values = (const float*)d_in[1];
    const float* W1     = (const float*)d_in[2];
    const float* b1     = (const float*)d_in[3];
    const float* W2     = (const float*)d_in[4];
    const float* b2     = (const float*)d_in[5];
    const float* Wv     = (const float*)d_in[6];
    // d_in[7] = bv: softmax is shift-invariant; scores aren't an output -> unused.

    float* out  = (float*)d_out;             // [B,D] context
    float* wout = out + B_SZ * D_DIM;        // [B,T] attention weights

    const size_t VN = (size_t)B_SZ * T_SZ * D_DIM;  // 64M elems
    char* ws = (char*)d_ws;
    unsigned short* vbf = (unsigned short*)ws;                     // 128 MB
    float* scores = (float*)(ws + VN * 2);                         // 256 KB
    float* qpb = scores + 65536;                                   // 128 KB
    unsigned short* W2t = (unsigned short*)(qpb + 32768);          // 2 MB
    float* part = (float*)W2t;  // aliases W2t (dead after gemm); 16*32*1024 f32 = 2 MB

    prep2<<<17920, 256, 0, stream>>>(values, vbf, W2, W2t, query, W1, b1, b2, qpb);
    score_gemm14<<<256, 512, 0, stream>>>(vbf, W2t, qpb, Wv, scores);
    softmax_k<<<B_SZ, 256, 0, stream>>>(scores, wout);
    context_part<<<dim3(B_SZ, 16), 256, 0, stream>>>(vbf, wout, part);
    context_red<<<B_SZ, 256, 0, stream>>>(part, out);
}

// Round 14
// 253.227 us; speedup vs baseline: 8.3928x; 1.0107x over previous
//
#include <hip/hip_runtime.h>
#include <hip/hip_bf16.h>

#define D_DIM 1024
#define U_DIM 1024
#define B_SZ  32
#define T_SZ  2048

typedef __bf16 bf16x8 __attribute__((ext_vector_type(8)));
typedef float f32x4 __attribute__((ext_vector_type(4)));
typedef unsigned short ushort8 __attribute__((ext_vector_type(8)));
typedef unsigned short ushort4_t __attribute__((ext_vector_type(4)));

#define AS1 __attribute__((address_space(1)))
#define AS3 __attribute__((address_space(3)))

__device__ __forceinline__ unsigned short f2bf(float f) {
    union { float f; unsigned u; } v;
    v.f = f;
    unsigned r = v.u + 0x7fffu + ((v.u >> 16) & 1u);  // RNE
    return (unsigned short)(r >> 16);
}
__device__ __forceinline__ float bf2f(unsigned short h) {
    union { unsigned u; float f; } v;
    v.u = (unsigned)h << 16;
    return v.f;
}

// ---------------- K1 (merged prep): w2t + qproj first (tail overlap), then vconv bulk ----------------
__global__ __launch_bounds__(256) void prep2(const float* __restrict__ v,
                                             unsigned short* __restrict__ vbf,
                                             const float* __restrict__ W2,
                                             unsigned short* __restrict__ W2t,
                                             const float* __restrict__ query,
                                             const float* __restrict__ W1,
                                             const float* __restrict__ b1,
                                             const float* __restrict__ b2,
                                             float* __restrict__ qpb) {
    __shared__ float tile[32][33];
    __shared__ float red[4][64];
    const int blk = blockIdx.x;
    const int tid = threadIdx.x;
    if (blk < 1024) {
        const int d0 = (blk & 31) * 32, u0 = (blk >> 5) * 32;
        const int tx = tid & 31, ty = tid >> 5;  // 32 x 8
#pragma unroll
        for (int i = 0; i < 4; i++)
            tile[ty + 8 * i][tx] = W2[(size_t)(d0 + ty + 8 * i) * U_DIM + u0 + tx];
        __syncthreads();
#pragma unroll
        for (int i = 0; i < 4; i++)
            W2t[(size_t)(u0 + ty + 8 * i) * D_DIM + d0 + tx] = f2bf(tile[tx][ty + 8 * i]);
    } else if (blk < 1536) {
        const int q = blk - 1024;          // 0..511
        const int b = q & 31;
        const int u0 = (q >> 5) * 64;
        const int ul = tid & 63, kq = tid >> 6;
        const int u = u0 + ul;
        float acc = 0.f;
        const float* qr = query + (size_t)b * D_DIM;
#pragma unroll 4
        for (int k = kq * 256; k < kq * 256 + 256; k++)
            acc += qr[k] * W1[(size_t)k * U_DIM + u];
        red[kq][ul] = acc;
        __syncthreads();
        if (tid < 64) {
            float s = red[0][tid] + red[1][tid] + red[2][tid] + red[3][tid];
            qpb[(size_t)b * U_DIM + u0 + tid] = s + b1[u0 + tid] + b2[u0 + tid];
        }
    } else {
        size_t i = ((size_t)(blk - 1536) * 256 + tid) * 16;
        f32x4 a0 = *reinterpret_cast<const f32x4*>(v + i);
        f32x4 a1 = *reinterpret_cast<const f32x4*>(v + i + 4);
        f32x4 a2 = *reinterpret_cast<const f32x4*>(v + i + 8);
        f32x4 a3 = *reinterpret_cast<const f32x4*>(v + i + 12);
        ushort8 h0, h1;
        h0[0] = f2bf(a0.x); h0[1] = f2bf(a0.y); h0[2] = f2bf(a0.z); h0[3] = f2bf(a0.w);
        h0[4] = f2bf(a1.x); h0[5] = f2bf(a1.y); h0[6] = f2bf(a1.z); h0[7] = f2bf(a1.w);
        h1[0] = f2bf(a2.x); h1[1] = f2bf(a2.y); h1[2] = f2bf(a2.z); h1[3] = f2bf(a2.w);
        h1[4] = f2bf(a3.x); h1[5] = f2bf(a3.y); h1[6] = f2bf(a3.z); h1[7] = f2bf(a3.w);
        *reinterpret_cast<ushort8*>(vbf + i) = h0;
        *reinterpret_cast<ushort8*>(vbf + i + 8) = h1;
    }
}

// ---------------- K3: fused score GEMM — 2-phase tiles (32 MFMA/phase), halved barriers ----------------
// Geometry as R12 (proven): 256 rows; 4 u-passes BN=256; BK=64; 64 K-tiles; 8 waves
// (wm2 x wn4); wave 128x64; acc[8][4] AGPR. LDS 2x64KB slots + qW/wV/red = 140 KB.
// Tile t (slot cb=t&1):
//   P1: read af0(8) + bq0(4) + bq1(4); stage Ah1(t+1); 32 MFMA (MH0 x both NH);
//       G1 vmcnt(8); barrier.
//   P2: read af1(8); stage Ah0,Bh0,Bh1(t+2); 32 MFMA (MH1); G2 vmcnt(8); barrier.
// Ledger (per wave, 2 loads/stage-op, chronological):
//   entering P1(t): [Ah1(t)] + [Ah0,Bh0,Bh1](t+1) = 8
//   P1(t) stages Ah1(t+1) -> 10; G1 vmcnt(8) retires Ah1(t)      (needed P2(t))
//   P2(t) stages [Ah0,Bh0,Bh1](t+2) -> 14; G2 vmcnt(8) retires [Ah0,Bh0,Bh1](t+1)
//       (needed P1(t+1)). Cover: A0/B 3 phases, Ah1 2 phases (phases ~2x longer).
// Prologue: 14 loads [A0,B0,B1,A1](0)+[A0,B0,B1](1); VMW(8) retires tile0's A0,B0,B1.
// Tail: t=62: G2 vmcnt(2); t=63: G1 vmcnt(0), G2 none.
// Slot WAR: Ah1(t+1) lands in slot cb^1 whose Ah1 was last read P2(t-1) (barrier before
// P1(t)); P2(t)'s stages land in slot cb halves last read at P1(t) (barrier between). ✓
__global__ __launch_bounds__(512, 2) void score_gemm15(const unsigned short* __restrict__ vbf,
                                                       const unsigned short* __restrict__ W2t,
                                                       const float* __restrict__ qpb,
                                                       const float* __restrict__ Wv,
                                                       float* __restrict__ scores) {
    __shared__ char smem[143360];
    float* qWl = (float*)(smem + 131072);   // 1024 f32
    float* wVl = (float*)(smem + 135168);   // 1024 f32
    float* redl = (float*)(smem + 139264);  // [4][256]

    const int tid = threadIdx.x, wave = tid >> 6, lane = tid & 63;
    const int lr = lane & 15, lk = lane >> 4;
    const int wm = wave >> 2, wn = wave & 3;
    const int row0 = blockIdx.x * 256;
    const int b = row0 >> 11;

    qWl[tid]       = qpb[(size_t)b * U_DIM + tid];
    qWl[tid + 512] = qpb[(size_t)b * U_DIM + tid + 512];
    wVl[tid]       = Wv[tid];
    wVl[tid + 512] = Wv[tid + 512];

    int pa[2], pb[2];
#pragma unroll
    for (int kk = 0; kk < 2; kk++) {
        pa[kk] = (wm * 128 + lr) * 128 + (((kk * 4 + lk) ^ (lr & 7)) << 4);
        pb[kk] = (wn * 64 + lr) * 128 + (((kk * 4 + lk) ^ (lr & 7)) << 4);
    }

    const int ecol = ((lane & 7) ^ (lane >> 3)) * 8;
    int aoff[2], dstA[2], boff[2], dstB[2];
#pragma unroll
    for (int j = 0; j < 2; j++) {
        const int rowA = j * 128 + wave * 8 + (lane >> 3);
        aoff[j] = (row0 + rowA) * 1024 + ecol;
        dstA[j] = j * 16384 + wave * 1024 + lane * 16;
        const int idx = wave * 2 + j, s = idx >> 2, l = idx & 3;
        const int rowB = s * 64 + l * 8 + (lane >> 3);
        boff[j] = rowB * 1024 + ecol;
        dstB[j] = 32768 + s * 8192 + l * 1024 + lane * 16;
    }

    auto SA2 = [&](int w, int h) {
#pragma unroll
        for (int j = 0; j < 2; j++)
            __builtin_amdgcn_global_load_lds(
                (const AS1 void*)(vbf + (size_t)(aoff[j] + h * 65536 + ((w & 15) << 6))),
                (AS3 void*)(smem + (w & 1) * 65536 + dstA[j] + h * 8192), 16, 0, 0);
    };
    auto SB2 = [&](int w, int h) {
#pragma unroll
        for (int j = 0; j < 2; j++)
            __builtin_amdgcn_global_load_lds(
                (const AS1 void*)(W2t + (size_t)(boff[j] + ((w >> 4) << 18) + h * 32768 +
                                                 ((w & 15) << 6))),
                (AS3 void*)(smem + (w & 1) * 65536 + dstB[j] + h * 4096), 16, 0, 0);
    };

    f32x4 acc[8][4] = {};
    float s_acc[8][4] = {};
    bf16x8 bq0[2][2], bq1[2][2];

#define VMW(N) asm volatile("s_waitcnt vmcnt(" #N ")" ::: "memory")
#define NOGATE (void)0
#define SBAR0 __builtin_amdgcn_sched_barrier(0);

#define RD_AF(CB, MH)                                                                 \
    _Pragma("unroll") for (int mi = 0; mi < 4; mi++)                                  \
        _Pragma("unroll") for (int kk = 0; kk < 2; kk++)                              \
            af[mi][kk] = *(const bf16x8*)(smem + (CB) + (MH) * 8192 + mi * 2048 + pa[kk]);
#define RD_BQ(BQ, CB, NH)                                                             \
    _Pragma("unroll") for (int ni = 0; ni < 2; ni++)                                  \
        _Pragma("unroll") for (int kk = 0; kk < 2; kk++)                              \
            BQ[ni][kk] = *(const bf16x8*)(smem + (CB) + 32768 + (NH) * 4096 + ni * 2048 + pb[kk]);

#define Q16(BQ, MB, NB2)                                                              \
    _Pragma("unroll") for (int kk = 0; kk < 2; kk++)                                  \
        _Pragma("unroll") for (int ni = 0; ni < 2; ni++)                              \
            _Pragma("unroll") for (int mi = 0; mi < 4; mi++)                          \
                acc[(MB) + mi][(NB2) + ni] = __builtin_amdgcn_mfma_f32_16x16x32_bf16( \
                    af[mi][kk], BQ[ni][kk], acc[(MB) + mi][(NB2) + ni], 0, 0, 0);

#define TILE(TT, CB, S1ON, S2ON, G1, G2)                                              \
    {                                                                                 \
        bf16x8 af[4][2];                                                              \
        /* P1: MH0 x {NH0,NH1} */                                                     \
        RD_AF(CB, 0)                                                                  \
        RD_BQ(bq0, CB, 0)                                                             \
        RD_BQ(bq1, CB, 1)                                                             \
        if (S1ON) SA2((TT) + 1, 1);                                                   \
        SBAR0                                                                         \
        __builtin_amdgcn_s_setprio(1);                                                \
        Q16(bq0, 0, 0) Q16(bq1, 0, 2)                                                 \
        __builtin_amdgcn_s_setprio(0);                                                \
        G1;                                                                           \
        __builtin_amdgcn_s_barrier();                                                 \
        /* P2: MH1 x {NH0,NH1} */                                                     \
        RD_AF(CB, 1)                                                                  \
        if (S2ON) { SA2((TT) + 2, 0); SB2((TT) + 2, 0); SB2((TT) + 2, 1); }           \
        SBAR0                                                                         \
        __builtin_amdgcn_s_setprio(1);                                                \
        Q16(bq0, 4, 0) Q16(bq1, 4, 2)                                                 \
        __builtin_amdgcn_s_setprio(0);                                                \
        G2;                                                                           \
        __builtin_amdgcn_s_barrier();                                                 \
    }

#define EPI(PS)                                                                     \
    {                                                                               \
        const int psv = (PS);                                                       \
        _Pragma("unroll") for (int n = 0; n < 4; n++) {                             \
            const int u = psv * 256 + wn * 64 + (n >> 1) * 32 + (n & 1) * 16 + lr;  \
            const float qv = qWl[u];                                                \
            const float wv = wVl[u];                                                \
            _Pragma("unroll") for (int m = 0; m < 8; m++)                           \
                _Pragma("unroll") for (int r = 0; r < 4; r++) {                     \
                    float x = acc[m][n][r] + qv;                                    \
                    float e = __expf(2.0f * x);                                     \
                    s_acc[m][r] += (1.0f - 2.0f / (e + 1.0f)) * wv;                 \
                    acc[m][n][r] = 0.f;                                             \
                }                                                                   \
        }                                                                           \
    }

    // prologue: [A0,B0,B1,A1](0) + [A0,B0,B1](1) = 14 loads; VMW(8) retires tile0 A0/B0/B1.
    asm volatile("s_waitcnt vmcnt(0) lgkmcnt(0)" ::: "memory");
    SA2(0, 0); SB2(0, 0); SB2(0, 1); SA2(0, 1);
    SA2(1, 0); SB2(1, 0); SB2(1, 1);
    VMW(8);
    __builtin_amdgcn_sched_barrier(0);
    __builtin_amdgcn_s_barrier();

#pragma unroll 1
    for (int s2 = 0; s2 < 31; ++s2) {
        const int te = 2 * s2;
        TILE(te, 0, 1, 1, VMW(8), VMW(8))
        TILE(te + 1, 65536, 1, 1, VMW(8), VMW(8))
        if ((s2 & 7) == 7) EPI(s2 >> 3)
    }
    TILE(62, 0, 1, 0, VMW(8), VMW(2))
    TILE(63, 65536, 0, 0, VMW(0), NOGATE)
    EPI(3)

#undef TILE
#undef Q16
#undef RD_AF
#undef RD_BQ
#undef SBAR0
#undef VMW
#undef NOGATE
#undef EPI

#pragma unroll
    for (int off = 1; off < 16; off <<= 1)
#pragma unroll
        for (int m = 0; m < 8; m++)
#pragma unroll
            for (int r = 0; r < 4; r++) s_acc[m][r] += __shfl_xor(s_acc[m][r], off);

    __syncthreads();
    if (lr == 0) {
#pragma unroll
        for (int m = 0; m < 8; m++)
#pragma unroll
            for (int r = 0; r < 4; r++)
                redl[wn * 256 + wm * 128 + (m >> 2) * 64 + (m & 3) * 16 + lk * 4 + r] = s_acc[m][r];
    }
    __syncthreads();
    if (tid < 256) {
        float s = redl[tid] + redl[256 + tid] + redl[512 + tid] + redl[768 + tid];
        scores[row0 + tid] = s;
    }
}

// ---------------- K4: softmax over T per batch ----------------
__global__ __launch_bounds__(256) void softmax_k(const float* __restrict__ scores,
                                                 float* __restrict__ wout) {
    int b = blockIdx.x, tid = threadIdx.x;
    int lane = tid & 63, wave = tid >> 6;
    __shared__ float redm[4], reds[4];
    float v[8];
    float mx = -3.4e38f;
#pragma unroll
    for (int i = 0; i < 8; i++) {
        v[i] = scores[(size_t)b * T_SZ + tid + i * 256];
        mx = fmaxf(mx, v[i]);
    }
#pragma unroll
    for (int off = 1; off < 64; off <<= 1) mx = fmaxf(mx, __shfl_xor(mx, off));
    if (lane == 0) redm[wave] = mx;
    __syncthreads();
    mx = fmaxf(fmaxf(redm[0], redm[1]), fmaxf(redm[2], redm[3]));
    float sum = 0.f;
#pragma unroll
    for (int i = 0; i < 8; i++) {
        v[i] = __expf(v[i] - mx);
        sum += v[i];
    }
#pragma unroll
    for (int off = 1; off < 64; off <<= 1) sum += __shfl_xor(sum, off);
    if (lane == 0) reds[wave] = sum;
    __syncthreads();
    sum = reds[0] + reds[1] + reds[2] + reds[3];
    float inv = 1.0f / sum;
#pragma unroll
    for (int i = 0; i < 8; i++) wout[(size_t)b * T_SZ + tid + i * 256] = v[i] * inv;
}

// ---------------- K5a: context partials — part[tc][b][d] = sum_{t in tc} w*v ----------------
__global__ __launch_bounds__(256) void context_part(const unsigned short* __restrict__ vbf,
                                                    const float* __restrict__ w,
                                                    float* __restrict__ part) {
    const int b = blockIdx.x, tc = blockIdx.y;
    const int d4 = threadIdx.x;
    f32x4 acc = {0.f, 0.f, 0.f, 0.f};
    const unsigned short* vb = vbf + (size_t)b * T_SZ * D_DIM;
    const int t0 = tc * 128;
#pragma unroll 2
    for (int t = t0; t < t0 + 128; ++t) {
        float wt = w[(size_t)b * T_SZ + t];
        ushort4_t hv = *reinterpret_cast<const ushort4_t*>(vb + (size_t)t * D_DIM + d4 * 4);
        acc.x += wt * bf2f(hv.x);
        acc.y += wt * bf2f(hv.y);
        acc.z += wt * bf2f(hv.z);
        acc.w += wt * bf2f(hv.w);
    }
    *reinterpret_cast<f32x4*>(part + ((size_t)tc * B_SZ + b) * D_DIM + d4 * 4) = acc;
}

// ---------------- K5b: context reduce — out[b][d] = sum_tc part[tc][b][d] ----------------
__global__ __launch_bounds__(256) void context_red(const float* __restrict__ part,
                                                   float* __restrict__ out) {
    const int b = blockIdx.x;
    const int d4 = threadIdx.x;
    f32x4 s = {0.f, 0.f, 0.f, 0.f};
#pragma unroll
    for (int p = 0; p < 16; ++p)
        s += *reinterpret_cast<const f32x4*>(part + ((size_t)p * B_SZ + b) * D_DIM + d4 * 4);
    *reinterpret_cast<f32x4*>(out + (size_t)b * D_DIM + d4 * 4) = s;
}

extern "C" void kernel_launch(void* const* d_in, const int* in_sizes, int n_in,
                              void* d_out, int out_size, void* d_ws, size_t ws_size,
                              hipStream_t stream) {
    (void)in_sizes; (void)n_in; (void)out_size; (void)ws_size;
    const float* query  = (const float*)d_in[0];
    const float* values = (const float*)d_in[1];
    const float* W1     = (const float*)d_in[2];
    const float* b1     = (const float*)d_in[3];
    const float* W2     = (const float*)d_in[4];
    const float* b2     = (const float*)d_in[5];
    const float* Wv     = (const float*)d_in[6];
    // d_in[7] = bv: softmax is shift-invariant; scores aren't an output -> unused.

    float* out  = (float*)d_out;             // [B,D] context
    float* wout = out + B_SZ * D_DIM;        // [B,T] attention weights

    const size_t VN = (size_t)B_SZ * T_SZ * D_DIM;  // 64M elems
    char* ws = (char*)d_ws;
    unsigned short* vbf = (unsigned short*)ws;                     // 128 MB
    float* scores = (float*)(ws + VN * 2);                         // 256 KB
    float* qpb = scores + 65536;                                   // 128 KB
    unsigned short* W2t = (unsigned short*)(qpb + 32768);          // 2 MB
    float* part = (float*)W2t;  // aliases W2t (dead after gemm); 16*32*1024 f32 = 2 MB

    prep2<<<17920, 256, 0, stream>>>(values, vbf, W2, W2t, query, W1, b1, b2, qpb);
    score_gemm15<<<256, 512, 0, stream>>>(vbf, W2t, qpb, Wv, scores);
    softmax_k<<<B_SZ, 256, 0, stream>>>(scores, wout);
    context_part<<<dim3(B_SZ, 16), 256, 0, stream>>>(vbf, wout, part);
    context_red<<<B_SZ, 256, 0, stream>>>(part, out);
}

// Round 15
// 251.915 us; speedup vs baseline: 8.4365x; 1.0052x over previous
//
#include <hip/hip_runtime.h>
#include <hip/hip_bf16.h>

#define D_DIM 1024
#define U_DIM 1024
#define B_SZ  32
#define T_SZ  2048

typedef __bf16 bf16x8 __attribute__((ext_vector_type(8)));
typedef float f32x4 __attribute__((ext_vector_type(4)));
typedef unsigned short ushort8 __attribute__((ext_vector_type(8)));
typedef unsigned short ushort4_t __attribute__((ext_vector_type(4)));

#define AS1 __attribute__((address_space(1)))
#define AS3 __attribute__((address_space(3)))

__device__ __forceinline__ unsigned short f2bf(float f) {
    union { float f; unsigned u; } v;
    v.f = f;
    unsigned r = v.u + 0x7fffu + ((v.u >> 16) & 1u);  // RNE
    return (unsigned short)(r >> 16);
}
__device__ __forceinline__ float bf2f(unsigned short h) {
    union { unsigned u; float f; } v;
    v.u = (unsigned)h << 16;
    return v.f;
}

// ---------------- K1 (merged prep): w2t + qproj first (tail overlap), then vconv bulk ----------------
__global__ __launch_bounds__(256) void prep2(const float* __restrict__ v,
                                             unsigned short* __restrict__ vbf,
                                             const float* __restrict__ W2,
                                             unsigned short* __restrict__ W2t,
                                             const float* __restrict__ query,
                                             const float* __restrict__ W1,
                                             const float* __restrict__ b1,
                                             const float* __restrict__ b2,
                                             float* __restrict__ qpb) {
    __shared__ float tile[32][33];
    __shared__ float red[4][64];
    const int blk = blockIdx.x;
    const int tid = threadIdx.x;
    if (blk < 1024) {
        const int d0 = (blk & 31) * 32, u0 = (blk >> 5) * 32;
        const int tx = tid & 31, ty = tid >> 5;  // 32 x 8
#pragma unroll
        for (int i = 0; i < 4; i++)
            tile[ty + 8 * i][tx] = W2[(size_t)(d0 + ty + 8 * i) * U_DIM + u0 + tx];
        __syncthreads();
#pragma unroll
        for (int i = 0; i < 4; i++)
            W2t[(size_t)(u0 + ty + 8 * i) * D_DIM + d0 + tx] = f2bf(tile[tx][ty + 8 * i]);
    } else if (blk < 1536) {
        const int q = blk - 1024;          // 0..511
        const int b = q & 31;
        const int u0 = (q >> 5) * 64;
        const int ul = tid & 63, kq = tid >> 6;
        const int u = u0 + ul;
        float acc = 0.f;
        const float* qr = query + (size_t)b * D_DIM;
#pragma unroll 4
        for (int k = kq * 256; k < kq * 256 + 256; k++)
            acc += qr[k] * W1[(size_t)k * U_DIM + u];
        red[kq][ul] = acc;
        __syncthreads();
        if (tid < 64) {
            float s = red[0][tid] + red[1][tid] + red[2][tid] + red[3][tid];
            qpb[(size_t)b * U_DIM + u0 + tid] = s + b1[u0 + tid] + b2[u0 + tid];
        }
    } else {
        size_t i = ((size_t)(blk - 1536) * 256 + tid) * 16;
        f32x4 a0 = *reinterpret_cast<const f32x4*>(v + i);
        f32x4 a1 = *reinterpret_cast<const f32x4*>(v + i + 4);
        f32x4 a2 = *reinterpret_cast<const f32x4*>(v + i + 8);
        f32x4 a3 = *reinterpret_cast<const f32x4*>(v + i + 12);
        ushort8 h0, h1;
        h0[0] = f2bf(a0.x); h0[1] = f2bf(a0.y); h0[2] = f2bf(a0.z); h0[3] = f2bf(a0.w);
        h0[4] = f2bf(a1.x); h0[5] = f2bf(a1.y); h0[6] = f2bf(a1.z); h0[7] = f2bf(a1.w);
        h1[0] = f2bf(a2.x); h1[1] = f2bf(a2.y); h1[2] = f2bf(a2.z); h1[3] = f2bf(a2.w);
        h1[4] = f2bf(a3.x); h1[5] = f2bf(a3.y); h1[6] = f2bf(a3.z); h1[7] = f2bf(a3.w);
        *reinterpret_cast<ushort8*>(vbf + i) = h0;
        *reinterpret_cast<ushort8*>(vbf + i + 8) = h1;
    }
}

// ---------------- K3: fused score GEMM — R14 structure (frozen; 158-160 µs proven) ----------------
__global__ __launch_bounds__(512, 2) void score_gemm15(const unsigned short* __restrict__ vbf,
                                                       const unsigned short* __restrict__ W2t,
                                                       const float* __restrict__ qpb,
                                                       const float* __restrict__ Wv,
                                                       float* __restrict__ scores) {
    __shared__ char smem[143360];
    float* qWl = (float*)(smem + 131072);   // 1024 f32
    float* wVl = (float*)(smem + 135168);   // 1024 f32
    float* redl = (float*)(smem + 139264);  // [4][256]

    const int tid = threadIdx.x, wave = tid >> 6, lane = tid & 63;
    const int lr = lane & 15, lk = lane >> 4;
    const int wm = wave >> 2, wn = wave & 3;
    const int row0 = blockIdx.x * 256;
    const int b = row0 >> 11;

    qWl[tid]       = qpb[(size_t)b * U_DIM + tid];
    qWl[tid + 512] = qpb[(size_t)b * U_DIM + tid + 512];
    wVl[tid]       = Wv[tid];
    wVl[tid + 512] = Wv[tid + 512];

    int pa[2], pb[2];
#pragma unroll
    for (int kk = 0; kk < 2; kk++) {
        pa[kk] = (wm * 128 + lr) * 128 + (((kk * 4 + lk) ^ (lr & 7)) << 4);
        pb[kk] = (wn * 64 + lr) * 128 + (((kk * 4 + lk) ^ (lr & 7)) << 4);
    }

    const int ecol = ((lane & 7) ^ (lane >> 3)) * 8;
    int aoff[2], dstA[2], boff[2], dstB[2];
#pragma unroll
    for (int j = 0; j < 2; j++) {
        const int rowA = j * 128 + wave * 8 + (lane >> 3);
        aoff[j] = (row0 + rowA) * 1024 + ecol;
        dstA[j] = j * 16384 + wave * 1024 + lane * 16;
        const int idx = wave * 2 + j, s = idx >> 2, l = idx & 3;
        const int rowB = s * 64 + l * 8 + (lane >> 3);
        boff[j] = rowB * 1024 + ecol;
        dstB[j] = 32768 + s * 8192 + l * 1024 + lane * 16;
    }

    auto SA2 = [&](int w, int h) {
#pragma unroll
        for (int j = 0; j < 2; j++)
            __builtin_amdgcn_global_load_lds(
                (const AS1 void*)(vbf + (size_t)(aoff[j] + h * 65536 + ((w & 15) << 6))),
                (AS3 void*)(smem + (w & 1) * 65536 + dstA[j] + h * 8192), 16, 0, 0);
    };
    auto SB2 = [&](int w, int h) {
#pragma unroll
        for (int j = 0; j < 2; j++)
            __builtin_amdgcn_global_load_lds(
                (const AS1 void*)(W2t + (size_t)(boff[j] + ((w >> 4) << 18) + h * 32768 +
                                                 ((w & 15) << 6))),
                (AS3 void*)(smem + (w & 1) * 65536 + dstB[j] + h * 4096), 16, 0, 0);
    };

    f32x4 acc[8][4] = {};
    float s_acc[8][4] = {};
    bf16x8 bq0[2][2], bq1[2][2];

#define VMW(N) asm volatile("s_waitcnt vmcnt(" #N ")" ::: "memory")
#define NOGATE (void)0
#define SBAR0 __builtin_amdgcn_sched_barrier(0);

#define RD_AF(CB, MH)                                                                 \
    _Pragma("unroll") for (int mi = 0; mi < 4; mi++)                                  \
        _Pragma("unroll") for (int kk = 0; kk < 2; kk++)                              \
            af[mi][kk] = *(const bf16x8*)(smem + (CB) + (MH) * 8192 + mi * 2048 + pa[kk]);
#define RD_BQ(BQ, CB, NH)                                                             \
    _Pragma("unroll") for (int ni = 0; ni < 2; ni++)                                  \
        _Pragma("unroll") for (int kk = 0; kk < 2; kk++)                              \
            BQ[ni][kk] = *(const bf16x8*)(smem + (CB) + 32768 + (NH) * 4096 + ni * 2048 + pb[kk]);

#define Q16(BQ, MB, NB2)                                                              \
    _Pragma("unroll") for (int kk = 0; kk < 2; kk++)                                  \
        _Pragma("unroll") for (int ni = 0; ni < 2; ni++)                              \
            _Pragma("unroll") for (int mi = 0; mi < 4; mi++)                          \
                acc[(MB) + mi][(NB2) + ni] = __builtin_amdgcn_mfma_f32_16x16x32_bf16( \
                    af[mi][kk], BQ[ni][kk], acc[(MB) + mi][(NB2) + ni], 0, 0, 0);

#define TILE(TT, CB, S1ON, S2ON, G1, G2)                                              \
    {                                                                                 \
        bf16x8 af[4][2];                                                              \
        RD_AF(CB, 0)                                                                  \
        RD_BQ(bq0, CB, 0)                                                             \
        RD_BQ(bq1, CB, 1)                                                             \
        if (S1ON) SA2((TT) + 1, 1);                                                   \
        SBAR0                                                                         \
        __builtin_amdgcn_s_setprio(1);                                                \
        Q16(bq0, 0, 0) Q16(bq1, 0, 2)                                                 \
        __builtin_amdgcn_s_setprio(0);                                                \
        G1;                                                                           \
        __builtin_amdgcn_s_barrier();                                                 \
        RD_AF(CB, 1)                                                                  \
        if (S2ON) { SA2((TT) + 2, 0); SB2((TT) + 2, 0); SB2((TT) + 2, 1); }           \
        SBAR0                                                                         \
        __builtin_amdgcn_s_setprio(1);                                                \
        Q16(bq0, 4, 0) Q16(bq1, 4, 2)                                                 \
        __builtin_amdgcn_s_setprio(0);                                                \
        G2;                                                                           \
        __builtin_amdgcn_s_barrier();                                                 \
    }

#define EPI(PS)                                                                     \
    {                                                                               \
        const int psv = (PS);                                                       \
        _Pragma("unroll") for (int n = 0; n < 4; n++) {                             \
            const int u = psv * 256 + wn * 64 + (n >> 1) * 32 + (n & 1) * 16 + lr;  \
            const float qv = qWl[u];                                                \
            const float wv = wVl[u];                                                \
            _Pragma("unroll") for (int m = 0; m < 8; m++)                           \
                _Pragma("unroll") for (int r = 0; r < 4; r++) {                     \
                    float x = acc[m][n][r] + qv;                                    \
                    float e = __expf(2.0f * x);                                     \
                    s_acc[m][r] += (1.0f - 2.0f / (e + 1.0f)) * wv;                 \
                    acc[m][n][r] = 0.f;                                             \
                }                                                                   \
        }                                                                           \
    }

    asm volatile("s_waitcnt vmcnt(0) lgkmcnt(0)" ::: "memory");
    SA2(0, 0); SB2(0, 0); SB2(0, 1); SA2(0, 1);
    SA2(1, 0); SB2(1, 0); SB2(1, 1);
    VMW(8);
    __builtin_amdgcn_sched_barrier(0);
    __builtin_amdgcn_s_barrier();

#pragma unroll 1
    for (int s2 = 0; s2 < 31; ++s2) {
        const int te = 2 * s2;
        TILE(te, 0, 1, 1, VMW(8), VMW(8))
        TILE(te + 1, 65536, 1, 1, VMW(8), VMW(8))
        if ((s2 & 7) == 7) EPI(s2 >> 3)
    }
    TILE(62, 0, 1, 0, VMW(8), VMW(2))
    TILE(63, 65536, 0, 0, VMW(0), NOGATE)
    EPI(3)

#undef TILE
#undef Q16
#undef RD_AF
#undef RD_BQ
#undef SBAR0
#undef VMW
#undef NOGATE
#undef EPI

#pragma unroll
    for (int off = 1; off < 16; off <<= 1)
#pragma unroll
        for (int m = 0; m < 8; m++)
#pragma unroll
            for (int r = 0; r < 4; r++) s_acc[m][r] += __shfl_xor(s_acc[m][r], off);

    __syncthreads();
    if (lr == 0) {
#pragma unroll
        for (int m = 0; m < 8; m++)
#pragma unroll
            for (int r = 0; r < 4; r++)
                redl[wn * 256 + wm * 128 + (m >> 2) * 64 + (m & 3) * 16 + lk * 4 + r] = s_acc[m][r];
    }
    __syncthreads();
    if (tid < 256) {
        float s = redl[tid] + redl[256 + tid] + redl[512 + tid] + redl[768 + tid];
        scores[row0 + tid] = s;
    }
}

// ---------------- K4 (fused): softmax + context partials ----------------
// Block (b, tc): recompute row-b softmax stats from scores (8 KB, L2-hot; redundant
// across tc but ~free); write wout slice [tc*128, tc*128+128) exactly once; compute
// context partial over those 128 t into part[tc][b][:].
__global__ __launch_bounds__(256) void context_sm(const unsigned short* __restrict__ vbf,
                                                  const float* __restrict__ scores,
                                                  float* __restrict__ wout,
                                                  float* __restrict__ part) {
    const int b = blockIdx.x, tc = blockIdx.y;
    const int tid = threadIdx.x;
    const int lane = tid & 63, wave = tid >> 6;
    __shared__ float redm[4], reds[4];
    __shared__ float wl[128];

    // row softmax stats (all 2048 scores)
    float v[8];
    float mx = -3.4e38f;
#pragma unroll
    for (int i = 0; i < 8; i++) {
        v[i] = scores[(size_t)b * T_SZ + tid + i * 256];
        mx = fmaxf(mx, v[i]);
    }
#pragma unroll
    for (int off = 1; off < 64; off <<= 1) mx = fmaxf(mx, __shfl_xor(mx, off));
    if (lane == 0) redm[wave] = mx;
    __syncthreads();
    mx = fmaxf(fmaxf(redm[0], redm[1]), fmaxf(redm[2], redm[3]));
    float sum = 0.f;
#pragma unroll
    for (int i = 0; i < 8; i++) sum += __expf(v[i] - mx);
#pragma unroll
    for (int off = 1; off < 64; off <<= 1) sum += __shfl_xor(sum, off);
    if (lane == 0) reds[wave] = sum;
    __syncthreads();
    sum = reds[0] + reds[1] + reds[2] + reds[3];
    const float inv = 1.0f / sum;

    // own 128-t weight slice -> LDS + wout (written exactly once per (b,t))
    if (tid < 128) {
        float s = scores[(size_t)b * T_SZ + tc * 128 + tid];
        float w = __expf(s - mx) * inv;
        wl[tid] = w;
        wout[(size_t)b * T_SZ + tc * 128 + tid] = w;
    }
    __syncthreads();

    // context partial over this slice
    const int d4 = tid;
    f32x4 acc = {0.f, 0.f, 0.f, 0.f};
    const unsigned short* vb = vbf + (size_t)b * T_SZ * D_DIM + (size_t)tc * 128 * D_DIM;
#pragma unroll 2
    for (int j = 0; j < 128; ++j) {
        float wt = wl[j];
        ushort4_t hv = *reinterpret_cast<const ushort4_t*>(vb + (size_t)j * D_DIM + d4 * 4);
        acc.x += wt * bf2f(hv.x);
        acc.y += wt * bf2f(hv.y);
        acc.z += wt * bf2f(hv.z);
        acc.w += wt * bf2f(hv.w);
    }
    *reinterpret_cast<f32x4*>(part + ((size_t)tc * B_SZ + b) * D_DIM + d4 * 4) = acc;
}

// ---------------- K5: context reduce — out[b][d] = sum_tc part[tc][b][d] ----------------
__global__ __launch_bounds__(256) void context_red(const float* __restrict__ part,
                                                   float* __restrict__ out) {
    const int b = blockIdx.x;
    const int d4 = threadIdx.x;
    f32x4 s = {0.f, 0.f, 0.f, 0.f};
#pragma unroll
    for (int p = 0; p < 16; ++p)
        s += *reinterpret_cast<const f32x4*>(part + ((size_t)p * B_SZ + b) * D_DIM + d4 * 4);
    *reinterpret_cast<f32x4*>(out + (size_t)b * D_DIM + d4 * 4) = s;
}

extern "C" void kernel_launch(void* const* d_in, const int* in_sizes, int n_in,
                              void* d_out, int out_size, void* d_ws, size_t ws_size,
                              hipStream_t stream) {
    (void)in_sizes; (void)n_in; (void)out_size; (void)ws_size;
    const float* query  = (const float*)d_in[0];
    const float* values = (const float*)d_in[1];
    const float* W1     = (const float*)d_in[2];
    const float* b1     = (const float*)d_in[3];
    const float* W2     = (const float*)d_in[4];
    const float* b2     = (const float*)d_in[5];
    const float* Wv     = (const float*)d_in[6];
    // d_in[7] = bv: softmax is shift-invariant; scores aren't an output -> unused.

    float* out  = (float*)d_out;             // [B,D] context
    float* wout = out + B_SZ * D_DIM;        // [B,T] attention weights

    const size_t VN = (size_t)B_SZ * T_SZ * D_DIM;  // 64M elems
    char* ws = (char*)d_ws;
    unsigned short* vbf = (unsigned short*)ws;                     // 128 MB
    float* scores = (float*)(ws + VN * 2);                         // 256 KB
    float* qpb = scores + 65536;                                   // 128 KB
    unsigned short* W2t = (unsigned short*)(qpb + 32768);          // 2 MB
    float* part = (float*)W2t;  // aliases W2t (dead after gemm); 16*32*1024 f32 = 2 MB

    prep2<<<17920, 256, 0, stream>>>(values, vbf, W2, W2t, query, W1, b1, b2, qpb);
    score_gemm15<<<256, 512, 0, stream>>>(vbf, W2t, qpb, Wv, scores);
    context_sm<<<dim3(B_SZ, 16), 256, 0, stream>>>(vbf, scores, wout, part);
    context_red<<<B_SZ, 256, 0, stream>>>(part, out);
}